// Round 7
// baseline (358.411 us; speedup 1.0000x reference)
//
#include <hip/hip_runtime.h>

#define N_TRACES 128
#define TLEN 32
#define IN_DIM 64
#define HID 128
#define G4 512
#define BATCH 4096
#define WGT 16   // traces per workgroup
#define NWG 8

typedef __attribute__((ext_vector_type(8))) short bf16x8; // 8 bf16 = 4 VGPRs (MFMA A/B frag)
typedef __attribute__((ext_vector_type(4))) float f32x4;  // MFMA C/D frag

__device__ __forceinline__ float fast_sigmoid(float x) {
    return 1.0f / (1.0f + __expf(-x));
}
__device__ __forceinline__ float fast_tanh(float x) {
    return 1.0f - 2.0f / (__expf(2.0f * x) + 1.0f);
}
// fp32 -> bf16 round-to-nearest-even (no NaN handling; inputs are tame)
__device__ __forceinline__ short f2bf(float f) {
    unsigned u = __float_as_uint(f);
    return (short)((u + 0x7FFFu + ((u >> 16) & 1u)) >> 16);
}
__device__ __forceinline__ float bf2f(short h) {
    return __uint_as_float(((unsigned)(unsigned short)h) << 16);
}

// ---------- input GEMM (unchanged, proven): xproj0 = input @ W_ih0^T + b_ih0 + b_hh0 ----------

template <int K>
__global__ __launch_bounds__(256) void gemm_bt(
    const float* __restrict__ A,
    const float* __restrict__ W,
    const float* __restrict__ b1,
    const float* __restrict__ b2,
    float* __restrict__ out,
    int Nld)
{
    constexpr int LD = 68;
    __shared__ float At[K][LD];
    __shared__ float Wt[K][LD];

    const int tid = threadIdx.x;
    const int m0 = blockIdx.x * 64;
    const int n0 = blockIdx.y * 64;

    const int rot = tid & 3;
    #pragma unroll
    for (int j = 0; j < K / 16; ++j) {
        const int e = 4 * (tid + 256 * j);
        const int row = e / K;
        const int k = e % K;
        float4 va = *(const float4*)(A + (size_t)(m0 + row) * K + k);
        float4 vw = *(const float4*)(W + (size_t)(n0 + row) * K + k);
        float fa[4] = {va.x, va.y, va.z, va.w};
        float fw[4] = {vw.x, vw.y, vw.z, vw.w};
        #pragma unroll
        for (int ii = 0; ii < 4; ++ii) {
            const int i = (ii + rot) & 3;
            At[k + i][row] = fa[i];
            Wt[k + i][row] = fw[i];
        }
    }
    __syncthreads();

    const int tx = tid & 15;
    const int ty = tid >> 4;
    float acc[4][4] = {};

    #pragma unroll 4
    for (int k = 0; k < K; ++k) {
        float4 a = *(const float4*)&At[k][ty * 4];
        float4 w = *(const float4*)&Wt[k][tx * 4];
        acc[0][0] = fmaf(a.x, w.x, acc[0][0]); acc[0][1] = fmaf(a.x, w.y, acc[0][1]);
        acc[0][2] = fmaf(a.x, w.z, acc[0][2]); acc[0][3] = fmaf(a.x, w.w, acc[0][3]);
        acc[1][0] = fmaf(a.y, w.x, acc[1][0]); acc[1][1] = fmaf(a.y, w.y, acc[1][1]);
        acc[1][2] = fmaf(a.y, w.z, acc[1][2]); acc[1][3] = fmaf(a.y, w.w, acc[1][3]);
        acc[2][0] = fmaf(a.z, w.x, acc[2][0]); acc[2][1] = fmaf(a.z, w.y, acc[2][1]);
        acc[2][2] = fmaf(a.z, w.z, acc[2][2]); acc[2][3] = fmaf(a.z, w.w, acc[2][3]);
        acc[3][0] = fmaf(a.w, w.x, acc[3][0]); acc[3][1] = fmaf(a.w, w.y, acc[3][1]);
        acc[3][2] = fmaf(a.w, w.z, acc[3][2]); acc[3][3] = fmaf(a.w, w.w, acc[3][3]);
    }

    float bb[4];
    #pragma unroll
    for (int j = 0; j < 4; ++j) {
        const int n = n0 + tx * 4 + j;
        bb[j] = b1[n] + b2[n];
    }
    #pragma unroll
    for (int i = 0; i < 4; ++i) {
        const int m = m0 + ty * 4 + i;
        float4 v;
        v.x = acc[i][0] + bb[0]; v.y = acc[i][1] + bb[1];
        v.z = acc[i][2] + bb[2]; v.w = acc[i][3] + bb[3];
        *(float4*)(out + (size_t)m * Nld + n0 + tx * 4) = v;
    }
}

// ---------- MFMA LSTM: 8 WGs x 16 traces, split-bf16 weights as A-frags ----------
// Wave q owns gate-tile quadruple {q, q+8, q+16, q+24} (rows q*16.. of gates
// i,f,g,o). MFMA 16x16x32_bf16: A[m=lane&15][k=quad*8+j], B[k=quad*8+j][n=lane&15],
// C[row=quad*4+r][col=lane&15] (m89/m91/m120-verified mappings). Lane ends each
// step holding i,f,g,o preacts for 4 (unit,trace) pairs -> in-register c-update.
// Split-bf16: W=Whi+Wlo, h=hhi+hlo; W@h ~= Whi*hhi + Whi*hlo + Wlo*hhi (err ~5e-5).

__global__ __launch_bounds__(512, 2) void lstm_mfma(
    const float* __restrict__ xproj0, // [4096][512] incl. layer-0 biases
    const float* __restrict__ Whh0,   // [512][128]
    const float* __restrict__ Wih1,   // [512][128]
    const float* __restrict__ bih1,   // [512]
    const float* __restrict__ bhh1,   // [512]
    const float* __restrict__ Whh1,   // [512][128]
    const float* __restrict__ Wlin,   // [128]
    const float* __restrict__ blin,   // [1]
    float* __restrict__ wsh1g,        // h1 B-frags: per WG 65536 floats
    float* __restrict__ wsxp1g,       // xp1 C-frags: per WG 262144 floats
    float* __restrict__ y)            // [4096]
{
    const int wg  = blockIdx.x;
    const int tid = threadIdx.x;
    const int l   = tid & 63;
    const int q   = tid >> 6;       // wave 0..7
    const int ln  = l & 15;         // trace-in-wg (B n / C col) and A row lane
    const int qd  = l >> 4;         // quad 0..3
    const int u0  = q * 16 + qd * 4; // first hidden unit of this lane's C rows

    __shared__ float hx[2][128 * 17];   // h exchange, u-major stride 17 (2-way reads)
    __shared__ float ypart[2][8][16];

    float* __restrict__ wsh1  = wsh1g  + (size_t)wg * (TLEN * 4 * 2 * 256);
    float* __restrict__ wsxp1 = wsxp1g + (size_t)wg * (TLEN * 8 * 4 * 256);

    bf16x8 Ah[4][4], Al[4][4]; // [gate tile i][k-tile]
    bf16x8 Bh[4], Bl[4];       // [k-tile]
    f32x4 xg[4];               // per-gate input projections for this lane's 4 rows
    float cc[4];

    auto load_A = [&](const float* W) {
        #pragma unroll
        for (int i = 0; i < 4; ++i) {
            const float* rp = W + (size_t)((q + 8 * i) * 16 + ln) * HID + qd * 8;
            #pragma unroll
            for (int kt = 0; kt < 4; ++kt) {
                float4 a = *(const float4*)(rp + kt * 32);
                float4 b = *(const float4*)(rp + kt * 32 + 4);
                float f[8] = {a.x, a.y, a.z, a.w, b.x, b.y, b.z, b.w};
                bf16x8 hi, lo;
                #pragma unroll
                for (int j = 0; j < 8; ++j) {
                    short hb = f2bf(f[j]);
                    hi[j] = hb;
                    lo[j] = f2bf(f[j] - bf2f(hb));
                }
                Ah[i][kt] = hi; Al[i][kt] = lo;
            }
        }
    };
    auto zero_B = [&]() {
        #pragma unroll
        for (int kt = 0; kt < 4; ++kt)
            #pragma unroll
            for (int j = 0; j < 8; ++j) { Bh[kt][j] = 0; Bl[kt][j] = 0; }
    };
    auto build_B = [&](const float* hbuf) {
        #pragma unroll
        for (int kt = 0; kt < 4; ++kt) {
            bf16x8 hi, lo;
            #pragma unroll
            for (int j = 0; j < 8; ++j) {
                float f = hbuf[(kt * 32 + qd * 8 + j) * 17 + ln];
                short hb = f2bf(f);
                hi[j] = hb; lo[j] = f2bf(f - bf2f(hb));
            }
            Bh[kt] = hi; Bl[kt] = lo;
        }
    };
    auto mfma_all = [&](f32x4 (&acc)[4]) {
        #pragma unroll
        for (int kt = 0; kt < 4; ++kt) {
            #pragma unroll
            for (int i = 0; i < 4; ++i) {
                acc[i] = __builtin_amdgcn_mfma_f32_16x16x32_bf16(Ah[i][kt], Bh[kt], acc[i], 0, 0, 0);
                acc[i] = __builtin_amdgcn_mfma_f32_16x16x32_bf16(Ah[i][kt], Bl[kt], acc[i], 0, 0, 0);
                acc[i] = __builtin_amdgcn_mfma_f32_16x16x32_bf16(Al[i][kt], Bh[kt], acc[i], 0, 0, 0);
            }
        }
    };

    // ===== Phase B: layer-0 recurrence =====
    load_A(Whh0);
    zero_B();
    #pragma unroll
    for (int r = 0; r < 4; ++r) cc[r] = 0.f;
    const float* xpbase = xproj0 + (size_t)(wg * WGT + ln) * TLEN * G4;
    #pragma unroll
    for (int i = 0; i < 4; ++i)
        xg[i] = *(const f32x4*)(xpbase + i * 128 + u0);

    #pragma unroll 1
    for (int t = 0; t < TLEN; ++t) {
        f32x4 acc[4] = {f32x4{0,0,0,0}, f32x4{0,0,0,0}, f32x4{0,0,0,0}, f32x4{0,0,0,0}};
        mfma_all(acc); // t=0: B is zero -> acc stays 0 (h(-1)=0)
        float h[4];
        #pragma unroll
        for (int r = 0; r < 4; ++r) {
            float iv = fast_sigmoid(acc[0][r] + xg[0][r]);
            float fv = fast_sigmoid(acc[1][r] + xg[1][r]);
            float gv = fast_tanh  (acc[2][r] + xg[2][r]);
            float ov = fast_sigmoid(acc[3][r] + xg[3][r]);
            cc[r] = fv * cc[r] + iv * gv;
            h[r]  = ov * fast_tanh(cc[r]);
        }
        float* hb = hx[t & 1];
        #pragma unroll
        for (int r = 0; r < 4; ++r) hb[(u0 + r) * 17 + ln] = h[r];
        __syncthreads();
        if (t + 1 < TLEN) {
            #pragma unroll
            for (int i = 0; i < 4; ++i)
                xg[i] = *(const f32x4*)(xpbase + (size_t)(t + 1) * G4 + i * 128 + u0);
        }
        build_B(hb);
        if (q == 0) { // publish B-frags for phase C (lane pattern is wave-independent)
            #pragma unroll
            for (int kt = 0; kt < 4; ++kt) {
                *(float4*)(wsh1 + ((size_t)(t * 4 + kt) * 2 + 0) * 256 + l * 4) = *(float4*)&Bh[kt];
                *(float4*)(wsh1 + ((size_t)(t * 4 + kt) * 2 + 1) * 256 + l * 4) = *(float4*)&Bl[kt];
            }
        }
    }
    __syncthreads(); // barrier's vmcnt drain publishes wave0's stores

    // ===== Phase C: xp1 = Wih1 @ h1 + biases (per-wave, barrier-free) =====
    load_A(Wih1);
    f32x4 bias[4];
    #pragma unroll
    for (int i = 0; i < 4; ++i) {
        f32x4 b1 = *(const f32x4*)(bih1 + (q + 8 * i) * 16 + qd * 4);
        f32x4 b2 = *(const f32x4*)(bhh1 + (q + 8 * i) * 16 + qd * 4);
        bias[i] = b1 + b2;
    }
    float4 bufA[8], bufB[8];
    auto loadBraw = [&](int t, float4 (&buf)[8]) {
        #pragma unroll
        for (int kt = 0; kt < 4; ++kt) {
            buf[kt * 2 + 0] = *(const float4*)(wsh1 + ((size_t)(t * 4 + kt) * 2 + 0) * 256 + l * 4);
            buf[kt * 2 + 1] = *(const float4*)(wsh1 + ((size_t)(t * 4 + kt) * 2 + 1) * 256 + l * 4);
        }
    };
    auto computeC = [&](int t, float4 (&buf)[8]) {
        f32x4 acc[4] = {f32x4{0,0,0,0}, f32x4{0,0,0,0}, f32x4{0,0,0,0}, f32x4{0,0,0,0}};
        #pragma unroll
        for (int kt = 0; kt < 4; ++kt) {
            bf16x8 bh = *(bf16x8*)&buf[kt * 2 + 0];
            bf16x8 bl = *(bf16x8*)&buf[kt * 2 + 1];
            #pragma unroll
            for (int i = 0; i < 4; ++i) {
                acc[i] = __builtin_amdgcn_mfma_f32_16x16x32_bf16(Ah[i][kt], bh, acc[i], 0, 0, 0);
                acc[i] = __builtin_amdgcn_mfma_f32_16x16x32_bf16(Ah[i][kt], bl, acc[i], 0, 0, 0);
                acc[i] = __builtin_amdgcn_mfma_f32_16x16x32_bf16(Al[i][kt], bh, acc[i], 0, 0, 0);
            }
        }
        #pragma unroll
        for (int i = 0; i < 4; ++i) {
            f32x4 o = acc[i] + bias[i];
            *(f32x4*)(wsxp1 + ((size_t)(t * 8 + q) * 4 + i) * 256 + l * 4) = o;
        }
    };
    loadBraw(0, bufA);
    #pragma unroll 1
    for (int tt = 0; tt < TLEN / 2; ++tt) {
        loadBraw(tt * 2 + 1, bufB);
        computeC(tt * 2, bufA);
        if (tt * 2 + 2 < TLEN) loadBraw(tt * 2 + 2, bufA);
        computeC(tt * 2 + 1, bufB);
    }
    __syncthreads(); // drain own stores before phase D reads them back

    // ===== Phase D: layer-1 recurrence + fused readout =====
    load_A(Whh1);
    f32x4 wl = *(const f32x4*)(Wlin + u0);
    float bl = blin[0];
    zero_B();
    #pragma unroll
    for (int r = 0; r < 4; ++r) cc[r] = 0.f;
    #pragma unroll
    for (int i = 0; i < 4; ++i)
        xg[i] = *(const f32x4*)(wsxp1 + ((size_t)(0 * 8 + q) * 4 + i) * 256 + l * 4);

    #pragma unroll 1
    for (int t = 0; t < TLEN; ++t) {
        f32x4 acc[4] = {f32x4{0,0,0,0}, f32x4{0,0,0,0}, f32x4{0,0,0,0}, f32x4{0,0,0,0}};
        mfma_all(acc);
        float h[4];
        #pragma unroll
        for (int r = 0; r < 4; ++r) {
            float iv = fast_sigmoid(acc[0][r] + xg[0][r]);
            float fv = fast_sigmoid(acc[1][r] + xg[1][r]);
            float gv = fast_tanh  (acc[2][r] + xg[2][r]);
            float ov = fast_sigmoid(acc[3][r] + xg[3][r]);
            cc[r] = fv * cc[r] + iv * gv;
            h[r]  = ov * fast_tanh(cc[r]);
        }
        // readout partial: this lane's 4 units, trace ln
        float p = wl[0] * h[0] + wl[1] * h[1] + wl[2] * h[2] + wl[3] * h[3];
        p += __shfl_xor(p, 16);
        p += __shfl_xor(p, 32);
        if (l < 16) ypart[t & 1][q][l] = p;
        float* hb = hx[t & 1];
        #pragma unroll
        for (int r = 0; r < 4; ++r) hb[(u0 + r) * 17 + ln] = h[r];
        __syncthreads();
        if (t + 1 < TLEN) {
            #pragma unroll
            for (int i = 0; i < 4; ++i)
                xg[i] = *(const f32x4*)(wsxp1 + ((size_t)((t + 1) * 8 + q) * 4 + i) * 256 + l * 4);
        }
        build_B(hb);
        if (q == 0 && l < 16) {
            float s = bl;
            #pragma unroll
            for (int ww = 0; ww < 8; ++ww) s += ypart[t & 1][ww][l];
            y[(size_t)(wg * WGT + l) * TLEN + t] = s;
        }
    }
}

// ---------- launch ----------

extern "C" void kernel_launch(void* const* d_in, const int* in_sizes, int n_in,
                              void* d_out, int out_size, void* d_ws, size_t ws_size,
                              hipStream_t stream) {
    const float* input = (const float*)d_in[0];  // [4096][64]
    const float* W_ih0 = (const float*)d_in[1];  // [512][64]
    const float* W_hh0 = (const float*)d_in[2];  // [512][128]
    const float* b_ih0 = (const float*)d_in[3];  // [512]
    const float* b_hh0 = (const float*)d_in[4];  // [512]
    const float* W_ih1 = (const float*)d_in[5];  // [512][128]
    const float* W_hh1 = (const float*)d_in[6];  // [512][128]
    const float* b_ih1 = (const float*)d_in[7];  // [512]
    const float* b_hh1 = (const float*)d_in[8];  // [512]
    const float* W_lin = (const float*)d_in[9];  // [1][128]
    const float* b_lin = (const float*)d_in[10]; // [1]
    float* out = (float*)d_out;                  // [4096]

    float* xproj0 = (float*)d_ws;                        // 2,097,152 floats (8 MB)
    float* wsh1   = xproj0 + (size_t)BATCH * G4;         // 8 WG * 65,536 floats (2 MB)
    float* wsxp1  = wsh1 + (size_t)NWG * TLEN * 4 * 2 * 256; // 8 WG * 262,144 floats (8 MB)

    dim3 ggrid(BATCH / 64, G4 / 64); // (64, 8)
    gemm_bt<IN_DIM><<<ggrid, 256, 0, stream>>>(input, W_ih0, b_ih0, b_hh0, xproj0, G4);
    lstm_mfma<<<NWG, 512, 0, stream>>>(xproj0, W_hh0, W_ih1, b_ih1, b_hh1,
                                       W_hh1, W_lin, b_lin, wsh1, wsxp1, out);
}

// Round 8
// 212.967 us; speedup vs baseline: 1.6829x; 1.6829x over previous
//
#include <hip/hip_runtime.h>

#define N_TRACES 128
#define TLEN 32
#define IN_DIM 64
#define HID 128
#define G4 512
#define BATCH (N_TRACES * TLEN)

// ---------- helpers ----------

__device__ __forceinline__ float fast_sigmoid(float x) {
    return 1.0f / (1.0f + __expf(-x));
}
__device__ __forceinline__ float fast_tanh(float x) {
    return 1.0f - 2.0f / (__expf(2.0f * x) + 1.0f);
}
// sum over lane pairs (xor1); both lanes get the pair sum
__device__ __forceinline__ float pair_reduce(float x) {
    x += __int_as_float(__builtin_amdgcn_update_dpp(
        0, __float_as_int(x), 0xB1 /*quad_perm [1,0,3,2]*/, 0xF, 0xF, true));
    return x;
}
// sum over quads (phase E only)
__device__ __forceinline__ float quad_reduce(float x) {
    x += __int_as_float(__builtin_amdgcn_update_dpp(
        0, __float_as_int(x), 0xB1, 0xF, 0xF, true));
    x += __int_as_float(__builtin_amdgcn_update_dpp(
        0, __float_as_int(x), 0x4E, 0xF, 0xF, true));
    return x;
}

// load 4 gate rows {u+128i} of W[512][ld], k-slice [sw*s, sw*s+sw)
template <int SW>
__device__ __forceinline__ void load_rows(const float* __restrict__ W, int ld,
                                          int u, int s, float (&w)[4][SW]) {
    #pragma unroll
    for (int i = 0; i < 4; ++i) {
        const float* wr = W + (size_t)(u + 128 * i) * ld + SW * s;
        #pragma unroll
        for (int j = 0; j < SW / 4; ++j) {
            float4 v = *(const float4*)(wr + 4 * j);
            w[i][4 * j + 0] = v.x; w[i][4 * j + 1] = v.y;
            w[i][4 * j + 2] = v.z; w[i][4 * j + 3] = v.w;
        }
    }
}

// acc[i] += dot(w[i][:], hb[0:SW]); hb 16B-aligned LDS
template <int SW>
__device__ __forceinline__ void matvec(const float (&w)[4][SW],
                                       const float* hb, float (&acc)[4]) {
    #pragma unroll
    for (int j = 0; j < SW / 4; ++j) {
        float4 v = *(const float4*)(hb + 4 * j);
        const float hx[4] = {v.x, v.y, v.z, v.w};
        #pragma unroll
        for (int e = 0; e < 4; ++e) {
            acc[0] = fmaf(w[0][4 * j + e], hx[e], acc[0]);
            acc[1] = fmaf(w[1][4 * j + e], hx[e], acc[1]);
            acc[2] = fmaf(w[2][4 * j + e], hx[e], acc[2]);
            acc[3] = fmaf(w[3][4 * j + e], hx[e], acc[3]);
        }
    }
}

// ---------- fully fused per-trace kernel: 256 threads, 4 waves = 1 wave/SIMD ----------
// Thread (u=tid>>1, s=tid&1) owns gate rows {u,128+u,256+u,384+u}, k-slice
// [64s,64s+64). Design rationale (r6 post-mortem): per-step issue is unchanged
// (~610 cyc/SIMD) but the barrier spans 4 waves instead of 8, gates run on ALL
// lanes (pair-redundant; no divergence), reduction is one DPP, and each wave
// owns its SIMD (no 2-wave round-robin on the serial chain). No global memory
// ops inside any recurrence loop (r5/r7 lesson: barrier drains vmcnt(0)).
// hs rows unpadded: a wave's reads are 2 broadcast addresses -> conflict-free.

__global__ __launch_bounds__(256) void lstm_fused(
    const float* __restrict__ input, // [4096][64]
    const float* __restrict__ Wih0,  // [512][64]
    const float* __restrict__ Whh0,  // [512][128]
    const float* __restrict__ bih0,  // [512]
    const float* __restrict__ bhh0,  // [512]
    const float* __restrict__ Wih1,  // [512][128]
    const float* __restrict__ Whh1,  // [512][128]
    const float* __restrict__ bih1,  // [512]
    const float* __restrict__ bhh1,  // [512]
    const float* __restrict__ Wlin,  // [128]
    const float* __restrict__ blin,  // [1]
    float* __restrict__ y)           // [4096]
{
    const int trace = blockIdx.x;
    const int tid = threadIdx.x;
    const int u = tid >> 1;
    const int s = tid & 1;

    __shared__ float xp[TLEN * G4];   // 64 KB: xproj0, overwritten by xproj1
    __shared__ float hs[TLEN][HID];   // 16 KB: x staging, then h1, then h2

    // ===== stage this trace's input (2048 floats) into hs region =====
    {
        const float4* src = (const float4*)(input + (size_t)trace * TLEN * IN_DIM);
        float4* dst = (float4*)&hs[0][0];
        dst[tid] = src[tid];
        dst[256 + tid] = src[256 + tid];
    }

    // ===== Phase A: xp[t] = Wih0 @ x(t) + b_ih0 + b_hh0 (t-parallel) =====
    {
        float w0[4][32];
        load_rows<32>(Wih0, IN_DIM, u, s, w0);
        float bb[4];
        #pragma unroll
        for (int i = 0; i < 4; ++i) bb[i] = bih0[u + 128 * i] + bhh0[u + 128 * i];
        __syncthreads(); // x staged
        #pragma unroll 1
        for (int t = 0; t < TLEN; ++t) {
            float acc[4] = {0.f, 0.f, 0.f, 0.f};
            matvec<32>(w0, &hs[0][0] + t * IN_DIM + 32 * s, acc);
            #pragma unroll
            for (int i = 0; i < 4; ++i) acc[i] = pair_reduce(acc[i]);
            if (s == 0) {
                #pragma unroll
                for (int i = 0; i < 4; ++i) xp[t * G4 + 128 * i + u] = acc[i] + bb[i];
            }
        }
    }
    __syncthreads(); // xp0 ready; hs free for h1

    // ===== Phase B: layer-0 recurrence (h1 -> hs) =====
    {
        float w[4][64];
        load_rows<64>(Whh0, HID, u, s, w);
        float cc = 0.f;
        #pragma unroll 1
        for (int t = 0; t < TLEN; ++t) {
            // xg first: depends only on t (xp stable all phase) -> schedules early
            const float xg0 = xp[t * G4 + u];
            const float xg1 = xp[t * G4 + 128 + u];
            const float xg2 = xp[t * G4 + 256 + u];
            const float xg3 = xp[t * G4 + 384 + u];
            float acc[4] = {0.f, 0.f, 0.f, 0.f};
            if (t > 0) matvec<64>(w, &hs[t - 1][64 * s], acc);
            #pragma unroll
            for (int i = 0; i < 4; ++i) acc[i] = pair_reduce(acc[i]);
            // gates on ALL lanes (pair-redundant): no divergence
            const float iv = fast_sigmoid(acc[0] + xg0);
            const float fv = fast_sigmoid(acc[1] + xg1);
            const float gv = fast_tanh(acc[2] + xg2);
            const float ov = fast_sigmoid(acc[3] + xg3);
            cc = fv * cc + iv * gv;
            const float h = ov * fast_tanh(cc);
            if (s == 0) hs[t][u] = h;
            __syncthreads();
        }
    }

    // ===== Phase C: xp[t] = Wih1 @ h1(t) + b_ih1 + b_hh1 (t-parallel, no barrier) =====
    {
        float w[4][64];
        load_rows<64>(Wih1, HID, u, s, w);
        float bi[4];
        #pragma unroll
        for (int i = 0; i < 4; ++i) bi[i] = bih1[u + 128 * i] + bhh1[u + 128 * i];
        #pragma unroll 1
        for (int t = 0; t < TLEN; ++t) {
            float acc[4] = {0.f, 0.f, 0.f, 0.f};
            matvec<64>(w, &hs[t][64 * s], acc);
            #pragma unroll
            for (int i = 0; i < 4; ++i) acc[i] = pair_reduce(acc[i]);
            if (s == 0) {
                #pragma unroll
                for (int i = 0; i < 4; ++i) xp[t * G4 + 128 * i + u] = acc[i] + bi[i];
            }
        }
    }
    __syncthreads(); // xp1 ready; h1 fully consumed

    // ===== Phase D: layer-1 recurrence (h2 overwrites hs) =====
    {
        float w[4][64];
        load_rows<64>(Whh1, HID, u, s, w);
        float cc = 0.f;
        #pragma unroll 1
        for (int t = 0; t < TLEN; ++t) {
            const float xg0 = xp[t * G4 + u];
            const float xg1 = xp[t * G4 + 128 + u];
            const float xg2 = xp[t * G4 + 256 + u];
            const float xg3 = xp[t * G4 + 384 + u];
            float acc[4] = {0.f, 0.f, 0.f, 0.f};
            if (t > 0) matvec<64>(w, &hs[t - 1][64 * s], acc);
            #pragma unroll
            for (int i = 0; i < 4; ++i) acc[i] = pair_reduce(acc[i]);
            const float iv = fast_sigmoid(acc[0] + xg0);
            const float fv = fast_sigmoid(acc[1] + xg1);
            const float gv = fast_tanh(acc[2] + xg2);
            const float ov = fast_sigmoid(acc[3] + xg3);
            cc = fv * cc + iv * gv;
            const float h = ov * fast_tanh(cc);
            if (s == 0) hs[t][u] = h;
            __syncthreads();
        }
    }

    // ===== Phase E: y[trace*32+t] = dot(h2(t), W_lin) + b_lin =====
    if (tid < 128) {
        const int tq = tid >> 2;
        const int sq = tid & 3;
        float wl[32];
        #pragma unroll
        for (int j = 0; j < 8; ++j) {
            float4 v = *(const float4*)(Wlin + 32 * sq + 4 * j);
            wl[4 * j + 0] = v.x; wl[4 * j + 1] = v.y;
            wl[4 * j + 2] = v.z; wl[4 * j + 3] = v.w;
        }
        const float* hb = &hs[tq][32 * sq];
        float a = 0.f;
        #pragma unroll
        for (int j = 0; j < 8; ++j) {
            float4 v = *(const float4*)(hb + 4 * j);
            a = fmaf(v.x, wl[4 * j + 0], a);
            a = fmaf(v.y, wl[4 * j + 1], a);
            a = fmaf(v.z, wl[4 * j + 2], a);
            a = fmaf(v.w, wl[4 * j + 3], a);
        }
        a = quad_reduce(a);
        if (sq == 0) y[trace * TLEN + tq] = a + blin[0];
    }
}

// ---------- launch ----------

extern "C" void kernel_launch(void* const* d_in, const int* in_sizes, int n_in,
                              void* d_out, int out_size, void* d_ws, size_t ws_size,
                              hipStream_t stream) {
    const float* input = (const float*)d_in[0];  // [4096][64]
    const float* W_ih0 = (const float*)d_in[1];  // [512][64]
    const float* W_hh0 = (const float*)d_in[2];  // [512][128]
    const float* b_ih0 = (const float*)d_in[3];  // [512]
    const float* b_hh0 = (const float*)d_in[4];  // [512]
    const float* W_ih1 = (const float*)d_in[5];  // [512][128]
    const float* W_hh1 = (const float*)d_in[6];  // [512][128]
    const float* b_ih1 = (const float*)d_in[7];  // [512]
    const float* b_hh1 = (const float*)d_in[8];  // [512]
    const float* W_lin = (const float*)d_in[9];  // [1][128]
    const float* b_lin = (const float*)d_in[10]; // [1]
    float* out = (float*)d_out;                  // [4096]

    // single kernel: everything trace-local, d_ws unused
    lstm_fused<<<N_TRACES, 256, 0, stream>>>(input, W_ih0, W_hh0, b_ih0, b_hh0,
                                             W_ih1, W_hh1, b_ih1, b_hh1,
                                             W_lin, b_lin, out);
}